// Round 5
// baseline (15334.982 us; speedup 1.0000x reference)
//
#include <hip/hip_runtime.h>
#include <math.h>

#define BATCHN 4096
#define DIMN 128
#define HIDN 100
#define NSTEPSN 50
#define KPAD 8192   // strict-lower 8128 padded to 8192
#define HPN 101     // 100 hidden + 1 bias row
#define HP4 104     // HPN padded to multiple of 4 (pad rows/cols = 0)
#define KSLICES 8   // k-split factor for TLP
#define WPS (16/KSLICES)  // 512-wide windows per slice

struct Weights {
  const float *W1d,*b1d,*W2d,*b2d,*W3d,*b3d,*Wod,*bod;
  const float *W1f,*b1f,*W2f,*b2f,*W3f,*b3f;
  const float *Wdiag,*bdiag;
};

// ---- k -> (row) for strict-lower packed index: k = r*(r-1)/2 + c, c<r
__device__ inline int tri_row(int k) {
  float rf = (1.0f + sqrtf(1.0f + 8.0f*(float)k)) * 0.5f;
  int r = (int)rf;
  if (k < (r*(r-1))/2) --r;
  else if (k >= (r*(r+1))/2) ++r;
  return r;
}
// fill_triangular: cat = [v[:,128:], v[:,::-1]]; element (r,c) of the 128x128
// reshape comes from v[kk+128] if kk<8128 else v[16383-kk], kk = r*128+c.
__device__ inline int cat_vidx(int r, int c) {
  int kk = r*128 + c;
  return (kk < 8128) ? (kk + 128) : (16383 - kk);
}

// ---- init: h-major permuted strict-lower output weights.
__global__ __launch_bounds__(256) void init_wperm(const float* __restrict__ Wo,
    const float* __restrict__ bo, float* __restrict__ Wperm)
{
  int idx = blockIdx.x*256 + threadIdx.x;
  if (idx >= HP4*KPAD) return;
  int h = idx >> 13, k = idx & (KPAD-1);
  float val = 0.f;
  if (k < 8128 && h <= HIDN) {
    int r = tri_row(k);
    int c = k - (r*(r-1))/2;
    int vidx = cat_vidx(r, c);
    val = (h < HIDN) ? Wo[h*8256 + vidx] : bo[vidx];
  }
  Wperm[idx] = val;
}

// ---- init: diagonal weight slice + diag bias
__global__ __launch_bounds__(256) void init_misc(const float* __restrict__ Wo,
    const float* __restrict__ bo, float* __restrict__ Wdiag,
    float* __restrict__ bdiag)
{
  int idx = blockIdx.x*256 + threadIdx.x;
  if (idx < HIDN*128) {
    int h = idx >> 7, r = idx & 127;
    Wdiag[idx] = Wo[h*8256 + cat_vidx(r, r)];
  } else if (idx < HIDN*128 + 128) {
    int r = idx - HIDN*128;
    bdiag[r] = bo[cat_vidx(r, r)];
  }
}

// ---- init: zero-padded Kx128 packs of the six narrow (.,100) matrices
__global__ __launch_bounds__(256) void init_pack(Weights wt, float* __restrict__ Wpack)
{
  int idx = blockIdx.x*256 + threadIdx.x;
  if (idx >= 6*128*128) return;
  int m = idx >> 14, rem = idx & 16383, c = rem >> 7, j = rem & 127;
  const float* src; int K;
  switch (m) {
    case 0: src = wt.W1d; K = 128; break;
    case 1: src = wt.W2d; K = 100; break;
    case 2: src = wt.W3d; K = 100; break;
    case 3: src = wt.W1f; K = 128; break;
    case 4: src = wt.W2f; K = 100; break;
    default: src = wt.W3f; K = 100; break;
  }
  Wpack[idx] = (j < HIDN && c < K) ? src[c*HIDN + j] : 0.f;
}

// ---- K1: both MLPs; W read straight from global (L1-served), barrier-free layers.
// 256 thr = 16 batches x 16 j-tiles; grid 256.
__global__ __launch_bounds__(256) void mlp_kernel(
    const float* __restrict__ xin, const float* __restrict__ Eprev,
    const float* __restrict__ yhat_prev,
    const float* __restrict__ z_t, Weights wt, const float* __restrict__ Wpack,
    float* __restrict__ xbase_out, float* __restrict__ h3b,
    float* __restrict__ hub_sum, float* __restrict__ ent_sum, int t)
{
  __shared__ float xinl[16*132];
  __shared__ float hA[16*132];
  __shared__ float hB[16*132];
  __shared__ float redw[4];
  __shared__ float redh[16];

  const int tid = threadIdx.x;
  const int b0 = blockIdx.x * 16;
  const int bb = tid >> 4;
  const int jt = tid & 15;
  const int j0 = jt * 8;

  // stage x tile (16x128), summing E partials, + fused Huber(t-1)
  {
    const int f = tid * 8;
    const int lb = f >> 7, c = f & 127;
    const float* xp = xin + (size_t)(b0+lb)*DIMN + c;
    float4 x0 = *(const float4*)xp;
    float4 x1 = *(const float4*)(xp+4);
    if (Eprev) {
      #pragma unroll
      for (int s = 0; s < KSLICES; ++s) {
        const float* ep = Eprev + ((size_t)s*BATCHN + b0+lb)*DIMN + c;
        const float4 e0 = *(const float4*)ep;
        const float4 e1 = *(const float4*)(ep+4);
        x0.x+=e0.x; x0.y+=e0.y; x0.z+=e0.z; x0.w+=e0.w;
        x1.x+=e1.x; x1.y+=e1.y; x1.z+=e1.z; x1.w+=e1.w;
      }
    }
    *(float4*)&xinl[lb*132+c]   = x0;
    *(float4*)&xinl[lb*132+c+4] = x1;
    if (yhat_prev) {
      const float* yp = yhat_prev + (size_t)(b0+lb)*DIMN + c;
      float4 y0 = *(const float4*)yp;
      float4 y1 = *(const float4*)(yp+4);
      float xv[8] = {x0.x,x0.y,x0.z,x0.w,x1.x,x1.y,x1.z,x1.w};
      float yv[8] = {y0.x,y0.y,y0.z,y0.w,y1.x,y1.y,y1.z,y1.w};
      float hub = 0.f;
      #pragma unroll
      for (int i=0;i<8;++i) {
        float e = xv[i]-yv[i], ae = fabsf(e);
        hub += (ae <= 0.5f) ? 0.5f*e*e : fmaf(0.5f, ae, -0.125f);
      }
      #pragma unroll
      for (int off=32; off>0; off>>=1) hub += __shfl_down(hub, off);
      if ((tid & 63) == 0) redw[tid>>6] = hub;
    }
  }
  __syncthreads();
  if (yhat_prev && tid == 0)
    atomicAdd(&hub_sum[t-1], redw[0]+redw[1]+redw[2]+redw[3]);

  float acc[8];

  // W rows from global: [c][128] row-major; lanes jt*8 -> coalesced 512B/row
  auto compute = [&](const float* inl, const float* __restrict__ Wg, int K) {
    #pragma unroll
    for (int i=0;i<8;++i) acc[i] = 0.f;
    const float* inrow = inl + bb*132;
    const float* wrow = Wg + j0;
    #pragma unroll 2
    for (int c4 = 0; c4 < K; c4 += 4) {
      const float4 xq = *(const float4*)&inrow[c4];
      const float xs[4] = {xq.x, xq.y, xq.z, xq.w};
      #pragma unroll
      for (int cc = 0; cc < 4; ++cc) {
        const float4 w0 = *(const float4*)&wrow[(size_t)(c4+cc)*128];
        const float4 w1 = *(const float4*)&wrow[(size_t)(c4+cc)*128 + 4];
        const float xv = xs[cc];
        acc[0] = fmaf(xv, w0.x, acc[0]);
        acc[1] = fmaf(xv, w0.y, acc[1]);
        acc[2] = fmaf(xv, w0.z, acc[2]);
        acc[3] = fmaf(xv, w0.w, acc[3]);
        acc[4] = fmaf(xv, w1.x, acc[4]);
        acc[5] = fmaf(xv, w1.y, acc[5]);
        acc[6] = fmaf(xv, w1.z, acc[6]);
        acc[7] = fmaf(xv, w1.w, acc[7]);
      }
    }
  };

  const float* P_W1d = Wpack;
  const float* P_W2d = Wpack + 16384;
  const float* P_W3d = Wpack + 32768;
  const float* P_W1f = Wpack + 49152;
  const float* P_W2f = Wpack + 65536;
  const float* P_W3f = Wpack + 81920;

  float h1reg[8], driftreg[8];

  // ---------- drift net ----------  (no barriers: h rows are thread-group-local)
  compute(xinl, P_W1d, 128);
  #pragma unroll
  for (int i=0;i<8;++i) {
    int j = j0+i;
    float v = (j < HIDN) ? tanhf(acc[i] + wt.b1d[j]) : 0.f;
    h1reg[i] = v; hA[bb*132+j] = v;
  }
  compute(hA, P_W2d, 100);
  #pragma unroll
  for (int i=0;i<8;++i) {
    int j = j0+i;
    float v = (j < HIDN) ? (tanhf(acc[i] + wt.b2d[j]) + h1reg[i]) : 0.f;
    hB[bb*132+j] = v;
  }
  compute(hB, P_W3d, 100);
  #pragma unroll
  for (int i=0;i<8;++i) {
    int j = j0+i;
    float v = (j < HIDN) ? fmaxf(acc[i] + wt.b3d[j], 0.f) : 0.f;
    hA[bb*132+j] = v;
  }
  compute(hA, wt.Wod, 100);
  #pragma unroll
  for (int i=0;i<8;++i) driftreg[i] = acc[i] + wt.bod[j0+i];

  // ---------- diff net ----------
  compute(xinl, P_W1f, 128);
  #pragma unroll
  for (int i=0;i<8;++i) {
    int j = j0+i;
    float v = (j < HIDN) ? tanhf(acc[i] + wt.b1f[j]) : 0.f;
    h1reg[i] = v; hB[bb*132+j] = v;
  }
  compute(hB, P_W2f, 100);
  #pragma unroll
  for (int i=0;i<8;++i) {
    int j = j0+i;
    float v = (j < HIDN) ? (tanhf(acc[i] + wt.b2f[j]) + h1reg[i]) : 0.f;
    hA[bb*132+j] = v;
  }
  compute(hA, P_W3f, 100);
  {
    float sv[8];
    #pragma unroll
    for (int i=0;i<8;++i) {
      int j = j0+i;
      float v = (j < HIDN) ? fmaxf(acc[i] + wt.b3f[j], 0.f) : 0.f;
      hB[bb*132+j] = v;
      sv[i] = (j < HIDN) ? v : ((j == HIDN) ? 1.f : 0.f);  // bias row + zero pads
    }
    if (j0 < HP4) {  // jt <= 12 covers [0,104)
      float* hp = h3b + (size_t)(b0+bb)*HP4 + j0;
      *(float4*)hp     = make_float4(sv[0],sv[1],sv[2],sv[3]);
      *(float4*)(hp+4) = make_float4(sv[4],sv[5],sv[6],sv[7]);
    }
  }
  compute(hB, wt.Wdiag, 100);

  // ---------- epilogue: vdiag, entropy, xbase ----------
  {
    float entacc = 0.f;
    const float* zp = z_t + (size_t)(b0+bb)*DIMN + j0;
    const float* xrow = xinl + bb*132 + j0;
    float o8[8];
    #pragma unroll
    for (int i=0;i<8;++i) {
      int j = j0+i;
      float vd = acc[i] + wt.bdiag[j];
      entacc += vd;                       // log(det) = sum of raw diag (log∘exp)
      o8[i] = xrow[i] + driftreg[i] + expf(vd) * zp[i];
    }
    float* bp = xbase_out + (size_t)(b0+bb)*DIMN + j0;
    *(float4*)bp     = make_float4(o8[0],o8[1],o8[2],o8[3]);
    *(float4*)(bp+4) = make_float4(o8[4],o8[5],o8[6],o8[7]);
    #pragma unroll
    for (int off=8; off>0; off>>=1) entacc += __shfl_down(entacc, off, 16);
    if (jt == 0) redh[bb] = entacc;
    __syncthreads();
    if (tid == 0) {
      float s = 0.f;
      #pragma unroll
      for (int i=0;i<16;++i) s += redh[i];
      atomicAdd(&ent_sum[t], s);
    }
  }
}

// ---- K2: partial V=h3aug@Wperm consumed into E-slice.
// KSLICES=8 -> 8 blocks/CU (16KB LDS) -> 8 waves/SIMD.
__global__ __launch_bounds__(256, 8) void heavy_kernel(
    const float* __restrict__ h3b,    // [4096][104]
    const float* __restrict__ Wperm,  // [104][8192] h-major
    const float* __restrict__ z_t,    // [4096][128]
    float* __restrict__ Eout)         // [KSLICES][4096][128]
{
  __shared__ float zl[16*128];
  __shared__ float El[16*128];

  const int tid = threadIdx.x;
  const int b0 = blockIdx.x * 16;
  const int slice = blockIdx.y;

  for (int i = tid; i < 16*128; i += 256) {
    int bbi = i >> 7, c = i & 127;
    zl[i] = z_t[(size_t)(b0+bbi)*DIMN + c];
    El[i] = 0.f;
  }
  __syncthreads();

  const int bq = tid >> 6;   // 0..3 : wave -> 4 batches
  const int kq = tid & 63;   // lane -> 8 consecutive k
  // h3 rows from global: wave-uniform float4 loads, L1-resident (6.6KB/block)
  const float* h3p0 = h3b + (size_t)(b0 + bq*4 + 0)*HP4;
  const float* h3p1 = h3b + (size_t)(b0 + bq*4 + 1)*HP4;
  const float* h3p2 = h3b + (size_t)(b0 + bq*4 + 2)*HP4;
  const float* h3p3 = h3b + (size_t)(b0 + bq*4 + 3)*HP4;

  for (int w = slice*WPS; w < slice*WPS + WPS; ++w) {
    const int k0 = w*512 + kq*8;
    float acc[4][8];
    #pragma unroll
    for (int bi=0;bi<4;++bi)
      #pragma unroll
      for (int i=0;i<8;++i) acc[bi][i] = 0.f;

    const float* wp = Wperm + k0;
    #pragma unroll 2
    for (int hc = 0; hc < HP4/4; ++hc) {
      float hcol[4][4];
      *(float4*)&hcol[0][0] = *(const float4*)&h3p0[hc*4];
      *(float4*)&hcol[1][0] = *(const float4*)&h3p1[hc*4];
      *(float4*)&hcol[2][0] = *(const float4*)&h3p2[hc*4];
      *(float4*)&hcol[3][0] = *(const float4*)&h3p3[hc*4];
      #pragma unroll
      for (int hh = 0; hh < 4; ++hh) {
        const size_t hrow = (size_t)(hc*4+hh)*KPAD;
        const float4 wa = *(const float4*)&wp[hrow];
        const float4 wb = *(const float4*)&wp[hrow + 4];
        const float w8[8] = {wa.x,wa.y,wa.z,wa.w, wb.x,wb.y,wb.z,wb.w};
        #pragma unroll
        for (int bi=0; bi<4; ++bi) {
          const float hv = hcol[bi][hh];
          #pragma unroll
          for (int i=0;i<8;++i) acc[bi][i] = fmaf(hv, w8[i], acc[bi][i]);
        }
      }
    }

    if (k0 < 8128) {   // 8-groups never straddle 8128 (both multiples of 8)
      int kr[8], kc[8];
      #pragma unroll
      for (int i=0;i<8;++i) {
        int k = k0 + i;
        int r = tri_row(k);
        kr[i] = r;
        kc[i] = k - (r*(r-1))/2;
      }
      #pragma unroll
      for (int bi=0;bi<4;++bi) {
        const int b = bq*4 + bi;
        float run = 0.f; int cur = kr[0];
        #pragma unroll
        for (int i=0;i<8;++i) {
          float p = acc[bi][i] * zl[b*128 + kc[i]];
          if (kr[i] == cur) run += p;
          else { atomicAdd(&El[b*128 + cur], run); cur = kr[i]; run = p; }
        }
        atomicAdd(&El[b*128 + cur], run);
      }
    }
  }
  __syncthreads();

  {
    float* eout = Eout + ((size_t)slice*BATCHN + b0)*DIMN;
    const int i = tid*8;
    *(float4*)&eout[i]   = *(const float4*)&El[i];
    *(float4*)&eout[i+4] = *(const float4*)&El[i+4];
  }
}

// ---- final-step huber: x = xbase + sum(E slices)
__global__ __launch_bounds__(256) void huber_kernel(const float* __restrict__ xb,
    const float* __restrict__ E, const float* __restrict__ y,
    float* __restrict__ dst)
{
  __shared__ float r[4];
  int idx = blockIdx.x*256 + threadIdx.x;
  float hub = 0.f;
  for (int i4 = idx; i4 < BATCHN*DIMN/4; i4 += 256*256) {
    float4 x = ((const float4*)xb)[i4];
    #pragma unroll
    for (int s=0;s<KSLICES;++s) {
      const float4 e = ((const float4*)E)[(size_t)s*(BATCHN*DIMN/4) + i4];
      x.x+=e.x; x.y+=e.y; x.z+=e.z; x.w+=e.w;
    }
    const float4 yv = ((const float4*)y)[i4];
    float ev[4] = {x.x-yv.x, x.y-yv.y, x.z-yv.z, x.w-yv.w};
    #pragma unroll
    for (int i=0;i<4;++i) {
      float ae = fabsf(ev[i]);
      hub += (ae <= 0.5f) ? 0.5f*ev[i]*ev[i] : fmaf(0.5f, ae, -0.125f);
    }
  }
  #pragma unroll
  for (int off=32; off>0; off>>=1) hub += __shfl_down(hub, off);
  if ((threadIdx.x & 63) == 0) r[threadIdx.x>>6] = hub;
  __syncthreads();
  if (threadIdx.x == 0) atomicAdd(dst, r[0]+r[1]+r[2]+r[3]);
}

__global__ void finalize_kernel(const float* __restrict__ hub_sum,
    const float* __restrict__ ent_sum, float* __restrict__ out)
{
  int i = threadIdx.x;
  if (i < NSTEPSN) {
    const float c1 = (1.0f/NSTEPSN)/(float)(BATCHN*DIMN);
    const float c2 = (1.0f/NSTEPSN)*0.0001f/(float)BATCHN;
    float s = 0.f;
    for (int j = NSTEPSN-1; j >= i; --j) s += hub_sum[j]*c1 - ent_sum[j]*c2;
    out[i] = s;
  }
}

extern "C" void kernel_launch(void* const* d_in, const int* in_sizes, int n_in,
                              void* d_out, int out_size, void* d_ws, size_t ws_size,
                              hipStream_t stream) {
  const float* init_state = (const float*)d_in[0];
  const float* yhat = (const float*)d_in[1];
  const float* z    = (const float*)d_in[2];
  Weights wt;
  wt.W1d = (const float*)d_in[5];  wt.b1d = (const float*)d_in[6];
  wt.W2d = (const float*)d_in[7];  wt.b2d = (const float*)d_in[8];
  wt.W3d = (const float*)d_in[9];  wt.b3d = (const float*)d_in[10];
  wt.Wod = (const float*)d_in[11]; wt.bod = (const float*)d_in[12];
  wt.W1f = (const float*)d_in[13]; wt.b1f = (const float*)d_in[14];
  wt.W2f = (const float*)d_in[15]; wt.b2f = (const float*)d_in[16];
  wt.W3f = (const float*)d_in[17]; wt.b3f = (const float*)d_in[18];
  const float* diff_Wo = (const float*)d_in[19];
  const float* diff_bo = (const float*)d_in[20];

  float* ws = (float*)d_ws;
  float* Wperm  = ws;                        // 104*8192 = 851968
  float* Wdiag  = Wperm + (size_t)HP4*KPAD;  // 12800
  float* bdiag  = Wdiag + HIDN*128;          // 128
  float* h3b    = bdiag + 128;               // 4096*104 = 425984
  float* xbA    = h3b + (size_t)BATCHN*HP4;  // 524288
  float* xbB    = xbA + (size_t)BATCHN*DIMN; // 524288
  float* Ebuf   = xbB + (size_t)BATCHN*DIMN; // 8*524288 = 4194304
  float* Wpack  = Ebuf + (size_t)KSLICES*BATCHN*DIMN; // 98304
  float* hub_sum = Wpack + 6*128*128;        // 64
  float* ent_sum = hub_sum + 64;             // 64

  wt.Wdiag = Wdiag; wt.bdiag = bdiag;

  hipMemsetAsync(hub_sum, 0, 128*sizeof(float), stream);
  init_wperm<<<(HP4*KPAD)/256, 256, 0, stream>>>(diff_Wo, diff_bo, Wperm);
  init_misc<<<(HIDN*128 + 128 + 255)/256, 256, 0, stream>>>(
      diff_Wo, diff_bo, Wdiag, bdiag);
  init_pack<<<(6*128*128)/256, 256, 0, stream>>>(wt, Wpack);

  const float* xin = init_state;
  const float* ein = nullptr;
  for (int t = 0; t < NSTEPSN; ++t) {
    float* xbout = (t & 1) ? xbB : xbA;
    const float* zt = z + (size_t)t*BATCHN*DIMN;
    const float* yp = t ? (yhat + (size_t)(t-1)*BATCHN*DIMN) : nullptr;
    mlp_kernel<<<256, 256, 0, stream>>>(xin, ein, yp, zt, wt, Wpack,
                                        xbout, h3b, hub_sum, ent_sum, t);
    heavy_kernel<<<dim3(256, KSLICES), 256, 0, stream>>>(h3b, Wperm, zt, Ebuf);
    xin = xbout; ein = Ebuf;
  }
  huber_kernel<<<256, 256, 0, stream>>>(xin, Ebuf,
      yhat + (size_t)(NSTEPSN-1)*BATCHN*DIMN, hub_sum + (NSTEPSN-1));
  finalize_kernel<<<1, 64, 0, stream>>>(hub_sum, ent_sum, (float*)d_out);
}

// Round 6
// 11769.159 us; speedup vs baseline: 1.3030x; 1.3030x over previous
//
#include <hip/hip_runtime.h>
#include <math.h>

#define BATCHN 4096
#define DIMN 128
#define HIDN 100
#define NSTEPSN 50
#define KPAD 8192   // strict-lower 8128 padded to 8192
#define HPN 101     // 100 hidden + 1 bias row
#define HP4 104     // HPN padded to multiple of 4 (pad rows/cols = 0)
#define KSLICES 8   // k-split factor for TLP (grid = 2048 = 8 blocks/CU)
#define WPS (16/KSLICES)  // 512-wide windows per slice
#define MB 8        // batches per mlp block

struct Weights {
  const float *W1d,*b1d,*W2d,*b2d,*W3d,*b3d,*Wod,*bod;
  const float *W1f,*b1f,*W2f,*b2f,*W3f,*b3f;
  const float *Wdiag,*bdiag;
};

// ---- k -> (row) for strict-lower packed index: k = r*(r-1)/2 + c, c<r
__device__ inline int tri_row(int k) {
  float rf = (1.0f + sqrtf(1.0f + 8.0f*(float)k)) * 0.5f;
  int r = (int)rf;
  if (k < (r*(r-1))/2) --r;
  else if (k >= (r*(r+1))/2) ++r;
  return r;
}
// fill_triangular: cat = [v[:,128:], v[:,::-1]]; element (r,c) of the 128x128
// reshape comes from v[kk+128] if kk<8128 else v[16383-kk], kk = r*128+c.
__device__ inline int cat_vidx(int r, int c) {
  int kk = r*128 + c;
  return (kk < 8128) ? (kk + 128) : (16383 - kk);
}

// ---- init: h-major permuted strict-lower output weights.
__global__ __launch_bounds__(256) void init_wperm(const float* __restrict__ Wo,
    const float* __restrict__ bo, float* __restrict__ Wperm)
{
  int idx = blockIdx.x*256 + threadIdx.x;
  if (idx >= HP4*KPAD) return;
  int h = idx >> 13, k = idx & (KPAD-1);
  float val = 0.f;
  if (k < 8128 && h <= HIDN) {
    int r = tri_row(k);
    int c = k - (r*(r-1))/2;
    int vidx = cat_vidx(r, c);
    val = (h < HIDN) ? Wo[h*8256 + vidx] : bo[vidx];
  }
  Wperm[idx] = val;
}

// ---- init: diagonal weight slice + diag bias
__global__ __launch_bounds__(256) void init_misc(const float* __restrict__ Wo,
    const float* __restrict__ bo, float* __restrict__ Wdiag,
    float* __restrict__ bdiag)
{
  int idx = blockIdx.x*256 + threadIdx.x;
  if (idx < HIDN*128) {
    int h = idx >> 7, r = idx & 127;
    Wdiag[idx] = Wo[h*8256 + cat_vidx(r, r)];
  } else if (idx < HIDN*128 + 128) {
    int r = idx - HIDN*128;
    bdiag[r] = bo[cat_vidx(r, r)];
  }
}

// ---- init: zero-padded Kx128 packs of the six narrow (.,100) matrices
__global__ __launch_bounds__(256) void init_pack(Weights wt, float* __restrict__ Wpack)
{
  int idx = blockIdx.x*256 + threadIdx.x;
  if (idx >= 6*128*128) return;
  int m = idx >> 14, rem = idx & 16383, c = rem >> 7, j = rem & 127;
  const float* src; int K;
  switch (m) {
    case 0: src = wt.W1d; K = 128; break;
    case 1: src = wt.W2d; K = 100; break;
    case 2: src = wt.W3d; K = 100; break;
    case 3: src = wt.W1f; K = 128; break;
    case 4: src = wt.W2f; K = 100; break;
    default: src = wt.W3f; K = 100; break;
  }
  Wpack[idx] = (j < HIDN && c < K) ? src[c*HIDN + j] : 0.f;
}

// ---- K1: both MLPs; 8 batches/block x 512 blocks (2 blocks/CU for TLP).
// 256 thr = 8 batches x 32 j-tiles(4). W streamed from global (L2-served).
__global__ __launch_bounds__(256) void mlp_kernel(
    const float* __restrict__ xin, const float* __restrict__ Eprev,
    const float* __restrict__ yhat_prev,
    const float* __restrict__ z_t, Weights wt, const float* __restrict__ Wpack,
    float* __restrict__ xbase_out, float* __restrict__ h3b,
    float* __restrict__ hub_sum, float* __restrict__ ent_sum, int t)
{
  __shared__ float xinl[MB*132];
  __shared__ float hA[MB*132];
  __shared__ float hB[MB*132];
  __shared__ float redw[4];
  __shared__ float redh[MB];

  const int tid = threadIdx.x;
  const int b0 = blockIdx.x * MB;
  const int bb = tid >> 5;       // 0..7 batch
  const int jt = tid & 31;       // 0..31 j-tile
  const int j0 = jt * 4;         // 0..124

  // stage x tile (8x128), summing E partials, + fused Huber(t-1)
  {
    const int f = tid * 4;
    const int lb = f >> 7, c = f & 127;
    const float* xp = xin + (size_t)(b0+lb)*DIMN + c;
    float4 x0 = *(const float4*)xp;
    if (Eprev) {
      #pragma unroll
      for (int s = 0; s < KSLICES; ++s) {
        const float4 e0 = *(const float4*)(Eprev + ((size_t)s*BATCHN + b0+lb)*DIMN + c);
        x0.x+=e0.x; x0.y+=e0.y; x0.z+=e0.z; x0.w+=e0.w;
      }
    }
    *(float4*)&xinl[lb*132+c] = x0;
    if (yhat_prev) {
      const float4 y0 = *(const float4*)(yhat_prev + (size_t)(b0+lb)*DIMN + c);
      float xv[4] = {x0.x,x0.y,x0.z,x0.w};
      float yv[4] = {y0.x,y0.y,y0.z,y0.w};
      float hub = 0.f;
      #pragma unroll
      for (int i=0;i<4;++i) {
        float e = xv[i]-yv[i], ae = fabsf(e);
        hub += (ae <= 0.5f) ? 0.5f*e*e : fmaf(0.5f, ae, -0.125f);
      }
      #pragma unroll
      for (int off=32; off>0; off>>=1) hub += __shfl_down(hub, off);
      if ((tid & 63) == 0) redw[tid>>6] = hub;
    }
  }
  __syncthreads();
  if (yhat_prev && tid == 0)
    atomicAdd(&hub_sum[t-1], redw[0]+redw[1]+redw[2]+redw[3]);

  float acc[4];

  // W rows from global: [c][128] row-major; 32 jt x 16B = 512B coalesced/row
  auto compute = [&](const float* inl, const float* __restrict__ Wg, int K) {
    #pragma unroll
    for (int i=0;i<4;++i) acc[i] = 0.f;
    const float* inrow = inl + bb*132;
    const float* wrow = Wg + j0;
    #pragma unroll 2
    for (int c4 = 0; c4 < K; c4 += 4) {
      const float4 xq = *(const float4*)&inrow[c4];
      const float xs[4] = {xq.x, xq.y, xq.z, xq.w};
      #pragma unroll
      for (int cc = 0; cc < 4; ++cc) {
        const float4 w0 = *(const float4*)&wrow[(size_t)(c4+cc)*128];
        const float xv = xs[cc];
        acc[0] = fmaf(xv, w0.x, acc[0]);
        acc[1] = fmaf(xv, w0.y, acc[1]);
        acc[2] = fmaf(xv, w0.z, acc[2]);
        acc[3] = fmaf(xv, w0.w, acc[3]);
      }
    }
  };

  const float* P_W1d = Wpack;
  const float* P_W2d = Wpack + 16384;
  const float* P_W3d = Wpack + 32768;
  const float* P_W1f = Wpack + 49152;
  const float* P_W2f = Wpack + 65536;
  const float* P_W3f = Wpack + 81920;

  float h1reg[4], driftreg[4];

  // ---------- drift net ---------- (barrier-free: h rows thread-group-local)
  compute(xinl, P_W1d, 128);
  #pragma unroll
  for (int i=0;i<4;++i) {
    int j = j0+i;
    float v = (j < HIDN) ? tanhf(acc[i] + wt.b1d[j]) : 0.f;
    h1reg[i] = v; hA[bb*132+j] = v;
  }
  compute(hA, P_W2d, 100);
  #pragma unroll
  for (int i=0;i<4;++i) {
    int j = j0+i;
    float v = (j < HIDN) ? (tanhf(acc[i] + wt.b2d[j]) + h1reg[i]) : 0.f;
    hB[bb*132+j] = v;
  }
  compute(hB, P_W3d, 100);
  #pragma unroll
  for (int i=0;i<4;++i) {
    int j = j0+i;
    float v = (j < HIDN) ? fmaxf(acc[i] + wt.b3d[j], 0.f) : 0.f;
    hA[bb*132+j] = v;
  }
  compute(hA, wt.Wod, 100);
  #pragma unroll
  for (int i=0;i<4;++i) driftreg[i] = acc[i] + wt.bod[j0+i];

  // ---------- diff net ----------
  compute(xinl, P_W1f, 128);
  #pragma unroll
  for (int i=0;i<4;++i) {
    int j = j0+i;
    float v = (j < HIDN) ? tanhf(acc[i] + wt.b1f[j]) : 0.f;
    h1reg[i] = v; hB[bb*132+j] = v;
  }
  compute(hB, P_W2f, 100);
  #pragma unroll
  for (int i=0;i<4;++i) {
    int j = j0+i;
    float v = (j < HIDN) ? (tanhf(acc[i] + wt.b2f[j]) + h1reg[i]) : 0.f;
    hA[bb*132+j] = v;
  }
  compute(hA, P_W3f, 100);
  {
    float sv[4];
    #pragma unroll
    for (int i=0;i<4;++i) {
      int j = j0+i;
      float v = (j < HIDN) ? fmaxf(acc[i] + wt.b3f[j], 0.f) : 0.f;
      hB[bb*132+j] = v;
      sv[i] = (j < HIDN) ? v : ((j == HIDN) ? 1.f : 0.f);  // bias row + zero pads
    }
    if (j0 <= 100) {  // jt <= 25 covers [0,104)
      float* hp = h3b + (size_t)(b0+bb)*HP4 + j0;
      *(float4*)hp = make_float4(sv[0],sv[1],sv[2],sv[3]);
    }
  }
  compute(hB, wt.Wdiag, 100);

  // ---------- epilogue: vdiag, entropy, xbase ----------
  {
    float entacc = 0.f;
    const float* zp = z_t + (size_t)(b0+bb)*DIMN + j0;
    const float* xrow = xinl + bb*132 + j0;
    float o4[4];
    #pragma unroll
    for (int i=0;i<4;++i) {
      int j = j0+i;
      float vd = acc[i] + wt.bdiag[j];
      entacc += vd;                       // log(det) = sum of raw diag (log∘exp)
      o4[i] = xrow[i] + driftreg[i] + expf(vd) * zp[i];
    }
    float* bp = xbase_out + (size_t)(b0+bb)*DIMN + j0;
    *(float4*)bp = make_float4(o4[0],o4[1],o4[2],o4[3]);
    #pragma unroll
    for (int off=16; off>0; off>>=1) entacc += __shfl_down(entacc, off, 32);
    if (jt == 0) redh[bb] = entacc;
    __syncthreads();
    if (tid == 0) {
      float s = 0.f;
      #pragma unroll
      for (int i=0;i<MB;++i) s += redh[i];
      atomicAdd(&ent_sum[t], s);
    }
  }
}

// ---- K2: partial V=h3aug@Wperm consumed into E-slice.
// KSLICES=8 -> 2048 blocks = 8 blocks/CU (16KB LDS) -> 8 waves/SIMD.
// launch_bounds (256,4): VGPR cap 128 — do NOT force 8 (R5: spilled to 32 VGPR).
__global__ __launch_bounds__(256, 4) void heavy_kernel(
    const float* __restrict__ h3b,    // [4096][104]
    const float* __restrict__ Wperm,  // [104][8192] h-major
    const float* __restrict__ z_t,    // [4096][128]
    float* __restrict__ Eout)         // [KSLICES][4096][128]
{
  __shared__ float zl[16*128];
  __shared__ float El[16*128];

  const int tid = threadIdx.x;
  const int b0 = blockIdx.x * 16;
  const int slice = blockIdx.y;

  for (int i = tid; i < 16*128; i += 256) {
    int bbi = i >> 7, c = i & 127;
    zl[i] = z_t[(size_t)(b0+bbi)*DIMN + c];
    El[i] = 0.f;
  }
  __syncthreads();

  const int bq = tid >> 6;   // 0..3 : wave -> 4 batches
  const int kq = tid & 63;   // lane -> 8 consecutive k
  // h3 rows from global: wave-uniform float4 loads, L1/L2-resident
  const float* h3p0 = h3b + (size_t)(b0 + bq*4 + 0)*HP4;
  const float* h3p1 = h3b + (size_t)(b0 + bq*4 + 1)*HP4;
  const float* h3p2 = h3b + (size_t)(b0 + bq*4 + 2)*HP4;
  const float* h3p3 = h3b + (size_t)(b0 + bq*4 + 3)*HP4;

  for (int w = slice*WPS; w < slice*WPS + WPS; ++w) {
    const int k0 = w*512 + kq*8;
    float acc[4][8];
    #pragma unroll
    for (int bi=0;bi<4;++bi)
      #pragma unroll
      for (int i=0;i<8;++i) acc[bi][i] = 0.f;

    const float* wp = Wperm + k0;
    #pragma unroll 2
    for (int hc = 0; hc < HP4/4; ++hc) {
      float hcol[4][4];
      *(float4*)&hcol[0][0] = *(const float4*)&h3p0[hc*4];
      *(float4*)&hcol[1][0] = *(const float4*)&h3p1[hc*4];
      *(float4*)&hcol[2][0] = *(const float4*)&h3p2[hc*4];
      *(float4*)&hcol[3][0] = *(const float4*)&h3p3[hc*4];
      #pragma unroll
      for (int hh = 0; hh < 4; ++hh) {
        const size_t hrow = (size_t)(hc*4+hh)*KPAD;
        const float4 wa = *(const float4*)&wp[hrow];
        const float4 wb = *(const float4*)&wp[hrow + 4];
        const float w8[8] = {wa.x,wa.y,wa.z,wa.w, wb.x,wb.y,wb.z,wb.w};
        #pragma unroll
        for (int bi=0; bi<4; ++bi) {
          const float hv = hcol[bi][hh];
          #pragma unroll
          for (int i=0;i<8;++i) acc[bi][i] = fmaf(hv, w8[i], acc[bi][i]);
        }
      }
    }

    if (k0 < 8128) {   // 8-groups never straddle 8128 (both multiples of 8)
      int kr[8], kc[8];
      #pragma unroll
      for (int i=0;i<8;++i) {
        int k = k0 + i;
        int r = tri_row(k);
        kr[i] = r;
        kc[i] = k - (r*(r-1))/2;
      }
      #pragma unroll
      for (int bi=0;bi<4;++bi) {
        const int b = bq*4 + bi;
        float run = 0.f; int cur = kr[0];
        #pragma unroll
        for (int i=0;i<8;++i) {
          float p = acc[bi][i] * zl[b*128 + kc[i]];
          if (kr[i] == cur) run += p;
          else { atomicAdd(&El[b*128 + cur], run); cur = kr[i]; run = p; }
        }
        atomicAdd(&El[b*128 + cur], run);
      }
    }
  }
  __syncthreads();

  {
    float* eout = Eout + ((size_t)slice*BATCHN + b0)*DIMN;
    const int i = tid*8;
    *(float4*)&eout[i]   = *(const float4*)&El[i];
    *(float4*)&eout[i+4] = *(const float4*)&El[i+4];
  }
}

// ---- final-step huber: x = xbase + sum(E slices)
__global__ __launch_bounds__(256) void huber_kernel(const float* __restrict__ xb,
    const float* __restrict__ E, const float* __restrict__ y,
    float* __restrict__ dst)
{
  __shared__ float r[4];
  int idx = blockIdx.x*256 + threadIdx.x;
  float hub = 0.f;
  for (int i4 = idx; i4 < BATCHN*DIMN/4; i4 += 256*256) {
    float4 x = ((const float4*)xb)[i4];
    #pragma unroll
    for (int s=0;s<KSLICES;++s) {
      const float4 e = ((const float4*)E)[(size_t)s*(BATCHN*DIMN/4) + i4];
      x.x+=e.x; x.y+=e.y; x.z+=e.z; x.w+=e.w;
    }
    const float4 yv = ((const float4*)y)[i4];
    float ev[4] = {x.x-yv.x, x.y-yv.y, x.z-yv.z, x.w-yv.w};
    #pragma unroll
    for (int i=0;i<4;++i) {
      float ae = fabsf(ev[i]);
      hub += (ae <= 0.5f) ? 0.5f*ev[i]*ev[i] : fmaf(0.5f, ae, -0.125f);
    }
  }
  #pragma unroll
  for (int off=32; off>0; off>>=1) hub += __shfl_down(hub, off);
  if ((threadIdx.x & 63) == 0) r[threadIdx.x>>6] = hub;
  __syncthreads();
  if (threadIdx.x == 0) atomicAdd(dst, r[0]+r[1]+r[2]+r[3]);
}

__global__ void finalize_kernel(const float* __restrict__ hub_sum,
    const float* __restrict__ ent_sum, float* __restrict__ out)
{
  int i = threadIdx.x;
  if (i < NSTEPSN) {
    const float c1 = (1.0f/NSTEPSN)/(float)(BATCHN*DIMN);
    const float c2 = (1.0f/NSTEPSN)*0.0001f/(float)BATCHN;
    float s = 0.f;
    for (int j = NSTEPSN-1; j >= i; --j) s += hub_sum[j]*c1 - ent_sum[j]*c2;
    out[i] = s;
  }
}

extern "C" void kernel_launch(void* const* d_in, const int* in_sizes, int n_in,
                              void* d_out, int out_size, void* d_ws, size_t ws_size,
                              hipStream_t stream) {
  const float* init_state = (const float*)d_in[0];
  const float* yhat = (const float*)d_in[1];
  const float* z    = (const float*)d_in[2];
  Weights wt;
  wt.W1d = (const float*)d_in[5];  wt.b1d = (const float*)d_in[6];
  wt.W2d = (const float*)d_in[7];  wt.b2d = (const float*)d_in[8];
  wt.W3d = (const float*)d_in[9];  wt.b3d = (const float*)d_in[10];
  wt.Wod = (const float*)d_in[11]; wt.bod = (const float*)d_in[12];
  wt.W1f = (const float*)d_in[13]; wt.b1f = (const float*)d_in[14];
  wt.W2f = (const float*)d_in[15]; wt.b2f = (const float*)d_in[16];
  wt.W3f = (const float*)d_in[17]; wt.b3f = (const float*)d_in[18];
  const float* diff_Wo = (const float*)d_in[19];
  const float* diff_bo = (const float*)d_in[20];

  float* ws = (float*)d_ws;
  float* Wperm  = ws;                        // 104*8192 = 851968
  float* Wdiag  = Wperm + (size_t)HP4*KPAD;  // 12800
  float* bdiag  = Wdiag + HIDN*128;          // 128
  float* h3b    = bdiag + 128;               // 4096*104 = 425984
  float* xbA    = h3b + (size_t)BATCHN*HP4;  // 524288
  float* xbB    = xbA + (size_t)BATCHN*DIMN; // 524288
  float* Ebuf   = xbB + (size_t)BATCHN*DIMN; // 8*524288 = 4194304
  float* Wpack  = Ebuf + (size_t)KSLICES*BATCHN*DIMN; // 98304
  float* hub_sum = Wpack + 6*128*128;        // 64
  float* ent_sum = hub_sum + 64;             // 64

  wt.Wdiag = Wdiag; wt.bdiag = bdiag;

  hipMemsetAsync(hub_sum, 0, 128*sizeof(float), stream);
  init_wperm<<<(HP4*KPAD)/256, 256, 0, stream>>>(diff_Wo, diff_bo, Wperm);
  init_misc<<<(HIDN*128 + 128 + 255)/256, 256, 0, stream>>>(
      diff_Wo, diff_bo, Wdiag, bdiag);
  init_pack<<<(6*128*128)/256, 256, 0, stream>>>(wt, Wpack);

  const float* xin = init_state;
  const float* ein = nullptr;
  for (int t = 0; t < NSTEPSN; ++t) {
    float* xbout = (t & 1) ? xbB : xbA;
    const float* zt = z + (size_t)t*BATCHN*DIMN;
    const float* yp = t ? (yhat + (size_t)(t-1)*BATCHN*DIMN) : nullptr;
    mlp_kernel<<<BATCHN/MB, 256, 0, stream>>>(xin, ein, yp, zt, wt, Wpack,
                                              xbout, h3b, hub_sum, ent_sum, t);
    heavy_kernel<<<dim3(256, KSLICES), 256, 0, stream>>>(h3b, Wperm, zt, Ebuf);
    xin = xbout; ein = Ebuf;
  }
  huber_kernel<<<256, 256, 0, stream>>>(xin, Ebuf,
      yhat + (size_t)(NSTEPSN-1)*BATCHN*DIMN, hub_sum + (NSTEPSN-1));
  finalize_kernel<<<1, 64, 0, stream>>>(hub_sum, ent_sum, (float*)d_out);
}